// Round 1
// baseline (1807.563 us; speedup 1.0000x reference)
//
#include <hip/hip_runtime.h>
#include <hip/hip_bf16.h>
#include <stdint.h>

// Problem constants (B,C,D,H,W fixed by the reference)
#define Bsz  64
#define Cch  4096
#define Npos 256     // D*H*W == CQ
#define CQn  256

typedef __attribute__((ext_vector_type(8))) short bf16x8;   // 8 bf16 (4 VGPRs)
typedef __attribute__((ext_vector_type(4))) short s16x4;
typedef __attribute__((ext_vector_type(4))) float f32x4;

static __device__ __forceinline__ unsigned short f2bf(float f){
  union { float f; uint32_t u; } v; v.f = f;
  uint32_t u = v.u;
  u += 0x7FFFu + ((u >> 16) & 1u);        // RNE
  return (unsigned short)(u >> 16);
}
static __device__ __forceinline__ float bf2f(unsigned short h){
  union { uint32_t u; float f; } v; v.u = ((uint32_t)h) << 16; return v.f;
}
static __device__ __forceinline__ void gload_lds16(const unsigned short* g, unsigned short* lds){
  __builtin_amdgcn_global_load_lds((const __attribute__((address_space(1))) void*)g,
                                   (__attribute__((address_space(3))) void*)lds, 16, 0, 0);
}

// ---------------------------------------------------------------------------
// prep: x [B][C][N] f32  ->  Xcat [(b,n)][8192] bf16 : cols 0..4095 = hi(x^T),
//                                                      cols 4096..8191 = lo(x^T)
// (transpose per batch so the q/k GEMM B-operand has contiguous k=c runs)
// ---------------------------------------------------------------------------
__global__ __launch_bounds__(256)
void split_x_kernel(const float* __restrict__ x, unsigned short* __restrict__ Xcat){
  __shared__ float tile[64][65];
  const int b = blockIdx.z, c0 = blockIdx.x * 64, n0 = blockIdx.y * 64;
  const float* xp = x + (size_t)b * Cch * Npos;
  const int t = threadIdx.x;
  #pragma unroll
  for (int p = 0; p < 16; ++p){
    int idx = p * 256 + t;
    int c = idx >> 6, n = idx & 63;
    tile[c][n] = xp[(size_t)(c0 + c) * Npos + n0 + n];
  }
  __syncthreads();
  #pragma unroll
  for (int p = 0; p < 16; ++p){
    int idx = p * 256 + t;
    int n = idx >> 6, c = idx & 63;
    float v = tile[c][n];
    unsigned short hi = f2bf(v);
    unsigned short lo = f2bf(v - bf2f(hi));
    size_t base = ((size_t)(b * 256 + n0 + n) << 13) + (size_t)(c0 + c);
    Xcat[base]        = hi;
    Xcat[base + 4096] = lo;
  }
}

// Acat [512][8192] bf16: rows 0..255 = [hi(Wq) | lo(Wq)], rows 256..511 = [hi(Wk) | lo(Wk)]
__global__ __launch_bounds__(256)
void prep_acat_kernel(const float* __restrict__ Wq, const float* __restrict__ Wk,
                      unsigned short* __restrict__ Acat){
  size_t i = (size_t)blockIdx.x * 256 + threadIdx.x;   // < 512*4096
  int m = (int)(i >> 12), c = (int)(i & 4095);
  float wv = (m < 256) ? Wq[i] : Wk[i - 1048576];
  unsigned short hi = f2bf(wv);
  unsigned short lo = f2bf(wv - bf2f(hi));
  Acat[((size_t)m << 13) + c]        = hi;
  Acat[((size_t)m << 13) + 4096 + c] = lo;
}

__global__ __launch_bounds__(256)
void cast_wv_kernel(const float* __restrict__ Wv, unsigned short* __restrict__ Wvh){
  size_t i = ((size_t)blockIdx.x * 256 + threadIdx.x) * 4;
  f32x4 v = *(const f32x4*)(Wv + i);
  s16x4 h;
  h[0] = (short)f2bf(v[0]); h[1] = (short)f2bf(v[1]);
  h[2] = (short)f2bf(v[2]); h[3] = (short)f2bf(v[3]);
  *(s16x4*)(Wvh + i) = h;
}

// ---------------------------------------------------------------------------
// Shared 128x128x(BK=64) bf16 MFMA GEMM, m97 structure.
//   A  : [M][ldA] bf16 row-major, fast-k
//   B  : [Ncols][ldB] bf16 (B^T storage), fast-k      (MODE 0,2)
//        or reg-staged from f32 x [b][c][n]           (MODE 1)
// MODE 0: q/k projection. K=12288 with folds: A k'->k' (<4096) else k'-4096;
//         B k'->k' (<8192) else k'-8192.  Out: q/k f32 [B][256][256] + bias.
// MODE 1: zT[b][i][c] = sum_n attn[b][i][n] * x[b][c][n], out bf16.
// MODE 2: out[b][c][i] = sum_k Wvh[c][k] zT[(b,i)][k] + bv[c], out f32.
// ---------------------------------------------------------------------------
template<int MODE>
__global__ __launch_bounds__(256)
void gemm128(const unsigned short* __restrict__ A, int ldA,
             const unsigned short* __restrict__ Bm, int ldB,
             const float* __restrict__ Bf32,
             const float* __restrict__ biasQ, const float* __restrict__ biasK,
             float* __restrict__ outQ, float* __restrict__ outK,
             unsigned short* __restrict__ outBF,
             float* __restrict__ outF, const float* __restrict__ biasV,
             int K)
{
  __shared__ __align__(16) unsigned short As[128 * 64];
  __shared__ __align__(16) unsigned short Bs[128 * 64];
  const int t = threadIdx.x;
  const int w = t >> 6, l = t & 63;
  const int wr = w >> 1, wc = w & 1;
  const int nt = blockIdx.x, mt = blockIdx.y, bz = blockIdx.z;
  const int row0 = mt * 128, col0 = nt * 128;

  const unsigned short* Ab = A;
  const float* xb = Bf32;
  if constexpr (MODE == 1) {
    Ab = A + (size_t)bz * (CQn * Npos);
    xb = Bf32 + (size_t)bz * ((size_t)Cch * Npos);
  }

  f32x4 acc[4][4];
  #pragma unroll
  for (int i = 0; i < 4; ++i)
    #pragma unroll
    for (int j = 0; j < 4; ++j) acc[i][j] = (f32x4){0.f, 0.f, 0.f, 0.f};

  const int lr8 = l >> 3;          // staging: row within 8-row group
  const int lk8 = (l & 7) * 8;     // staging: k element offset
  const int fl  = l & 15;          // fragment row/col lane
  const int fk  = (l >> 4) * 8;    // fragment k offset (contiguous-8 layout, m92-verified)

  const int nsteps = K >> 6;
  for (int kt = 0; kt < nsteps; ++kt){
    const int k0 = kt << 6;
    __syncthreads();
    // ---- stage A tile (global_load_lds width 16) ----
    {
      int ak = k0;
      if constexpr (MODE == 0) ak = (k0 < 4096) ? k0 : k0 - 4096;
      const unsigned short* Ab2 = Ab + (size_t)row0 * ldA + ak + lk8;
      #pragma unroll
      for (int r = 0; r < 4; ++r){
        int rr = r * 32 + w * 8 + lr8;
        gload_lds16(Ab2 + (size_t)rr * ldA, &As[(r * 32 + w * 8) * 64]);
      }
    }
    // ---- stage B tile ----
    if constexpr (MODE == 1){
      // reg-stage from f32 x: Bs[c][n], convert to bf16 on the fly
      #pragma unroll
      for (int p = 0; p < 8; ++p){
        int c = p * 16 + (t >> 4);
        int slot = t & 15;
        f32x4 v = *(const f32x4*)(xb + (size_t)(col0 + c) * Npos + k0 + slot * 4);
        s16x4 h;
        h[0] = (short)f2bf(v[0]); h[1] = (short)f2bf(v[1]);
        h[2] = (short)f2bf(v[2]); h[3] = (short)f2bf(v[3]);
        *(s16x4*)&Bs[c * 64 + slot * 4] = h;
      }
    } else {
      int bk = k0;
      if constexpr (MODE == 0) bk = (k0 < 8192) ? k0 : k0 - 8192;
      const unsigned short* Bb2 = Bm + (size_t)col0 * ldB + bk + lk8;
      #pragma unroll
      for (int r = 0; r < 4; ++r){
        int rr = r * 32 + w * 8 + lr8;
        gload_lds16(Bb2 + (size_t)rr * ldB, &Bs[(r * 32 + w * 8) * 64]);
      }
    }
    __syncthreads();
    // ---- compute: 2 x (4x4) MFMA 16x16x32 ----
    #pragma unroll
    for (int kk = 0; kk < 2; ++kk){
      bf16x8 af[4], bfr[4];
      #pragma unroll
      for (int mi = 0; mi < 4; ++mi)
        af[mi] = *(const bf16x8*)&As[(wr * 64 + mi * 16 + fl) * 64 + kk * 32 + fk];
      #pragma unroll
      for (int nj = 0; nj < 4; ++nj)
        bfr[nj] = *(const bf16x8*)&Bs[(wc * 64 + nj * 16 + fl) * 64 + kk * 32 + fk];
      #pragma unroll
      for (int mi = 0; mi < 4; ++mi)
        #pragma unroll
        for (int nj = 0; nj < 4; ++nj)
          acc[mi][nj] = __builtin_amdgcn_mfma_f32_16x16x32_bf16(af[mi], bfr[nj], acc[mi][nj], 0, 0, 0);
    }
  }

  // ---- epilogue (D mapping: col = lane&15, row = (lane>>4)*4 + r  [m89/m91]) ----
  const int lrow = (l >> 4) * 4;
  #pragma unroll
  for (int mi = 0; mi < 4; ++mi){
    #pragma unroll
    for (int nj = 0; nj < 4; ++nj){
      int col = col0 + wc * 64 + nj * 16 + fl;
      f32x4 v = acc[mi][nj];
      #pragma unroll
      for (int r = 0; r < 4; ++r){
        int row = row0 + wr * 64 + mi * 16 + lrow + r;
        if constexpr (MODE == 0){
          int b = col >> 8, n = col & 255;
          float bia = (row < 256) ? biasQ[row] : biasK[row - 256];
          float* dst = (row < 256) ? outQ : outK;
          dst[((size_t)b << 16) + ((size_t)(row & 255) << 8) + n] = v[r] + bia;
        } else if constexpr (MODE == 1){
          outBF[(size_t)bz * ((size_t)CQn * Cch) + (size_t)row * Cch + col] = f2bf(v[r]);
        } else {
          int b = col >> 8, i2 = col & 255;
          outF[(size_t)b * ((size_t)Cch * Npos) + (size_t)row * Npos + i2] = v[r] + biasV[row];
        }
      }
    }
  }
}

// ---------------------------------------------------------------------------
// energy[b][i][j] = sum_n q[b][i][n] * k[b][j][n]   (fp32 vector, NT GEMM)
// ---------------------------------------------------------------------------
__global__ __launch_bounds__(256)
void energy_kernel(const float* __restrict__ q, const float* __restrict__ k,
                   float* __restrict__ e){
  const int b = blockIdx.z;
  const int i0 = blockIdx.y * 64, j0 = blockIdx.x * 64;
  const float* qb = q + ((size_t)b << 16);
  const float* kb = k + ((size_t)b << 16);
  float* eb = e + ((size_t)b << 16);
  __shared__ float Qs[64][33];
  __shared__ float Ks[64][33];
  const int t = threadIdx.x;
  const int tx = t & 15, ty = t >> 4;
  float accv[4][4];
  #pragma unroll
  for (int ii = 0; ii < 4; ++ii)
    #pragma unroll
    for (int jj = 0; jj < 4; ++jj) accv[ii][jj] = 0.f;

  for (int n0 = 0; n0 < 256; n0 += 32){
    __syncthreads();
    #pragma unroll
    for (int p = 0; p < 8; ++p){
      int idx = p * 256 + t;
      int r = idx >> 5, n = idx & 31;
      Qs[r][n] = qb[(size_t)(i0 + r) * 256 + n0 + n];
      Ks[r][n] = kb[(size_t)(j0 + r) * 256 + n0 + n];
    }
    __syncthreads();
    #pragma unroll
    for (int n = 0; n < 32; ++n){
      float a4[4], b4[4];
      #pragma unroll
      for (int ii = 0; ii < 4; ++ii) a4[ii] = Qs[ty * 4 + ii][n];
      #pragma unroll
      for (int jj = 0; jj < 4; ++jj) b4[jj] = Ks[tx * 4 + jj][n];
      #pragma unroll
      for (int ii = 0; ii < 4; ++ii)
        #pragma unroll
        for (int jj = 0; jj < 4; ++jj) accv[ii][jj] = fmaf(a4[ii], b4[jj], accv[ii][jj]);
    }
  }
  #pragma unroll
  for (int ii = 0; ii < 4; ++ii){
    f32x4 o;
    #pragma unroll
    for (int jj = 0; jj < 4; ++jj) o[jj] = accv[ii][jj];
    *(f32x4*)&eb[(size_t)(i0 + ty * 4 + ii) * 256 + j0 + tx * 4] = o;
  }
}

// softmax over last axis (256), write bf16 attn
__global__ __launch_bounds__(256)
void softmax_kernel(const float* __restrict__ e, unsigned short* __restrict__ attn){
  const size_t row = blockIdx.x;
  const int t = threadIdx.x;
  float v = e[(row << 8) + t];
  float m = v;
  #pragma unroll
  for (int off = 32; off >= 1; off >>= 1) m = fmaxf(m, __shfl_xor(m, off));
  __shared__ float red[8];
  if ((t & 63) == 0) red[t >> 6] = m;
  __syncthreads();
  m = fmaxf(fmaxf(red[0], red[1]), fmaxf(red[2], red[3]));
  float p = __expf(v - m);
  float s = p;
  #pragma unroll
  for (int off = 32; off >= 1; off >>= 1) s += __shfl_xor(s, off);
  if ((t & 63) == 0) red[4 + (t >> 6)] = s;
  __syncthreads();
  s = red[4] + red[5] + red[6] + red[7];
  attn[(row << 8) + t] = f2bf(p / s);
}

// ---------------------------------------------------------------------------
extern "C" void kernel_launch(void* const* d_in, const int* in_sizes, int n_in,
                              void* d_out, int out_size, void* d_ws, size_t ws_size,
                              hipStream_t stream){
  const float* x  = (const float*)d_in[0];
  const float* Wq = (const float*)d_in[1];
  const float* bq = (const float*)d_in[2];
  const float* Wk = (const float*)d_in[3];
  const float* bk = (const float*)d_in[4];
  const float* Wv = (const float*)d_in[5];
  const float* bv = (const float*)d_in[6];

  // workspace layout (310,378,496 B total):
  //   [0, 268435456)              Xcat bf16 [16384][8192]  (hi | lo of x^T)
  //   [0, 134217728)  (overlay)   zT bf16 [16384][4096]    (written after Xcat dead)
  //   [268435456, +8388608)       Acat bf16 [512][8192]
  //   [276824064, +33554432)      Wvh  bf16 [4096][4096]
  char* ws = (char*)d_ws;
  unsigned short* Xcat = (unsigned short*)ws;
  unsigned short* zT   = (unsigned short*)ws;                       // overlay, see above
  unsigned short* Acat = (unsigned short*)(ws + 268435456u);
  unsigned short* Wvh  = (unsigned short*)(ws + 268435456u + 8388608u);

  // d_out doubles as scratch for q/k/energy/attn (all dead before the final GEMM)
  char* ob = (char*)d_out;
  float* q            = (float*)ob;                       // 16.8 MB
  float* k            = (float*)(ob + 16777216u);         // 16.8 MB
  float* en           = (float*)(ob + 33554432u);         // 16.8 MB
  unsigned short* atb = (unsigned short*)(ob + 50331648u);// 8.4 MB
  float* outF         = (float*)d_out;

  split_x_kernel<<<dim3(64, 4, 64), 256, 0, stream>>>(x, Xcat);
  prep_acat_kernel<<<8192, 256, 0, stream>>>(Wq, Wk, Acat);
  cast_wv_kernel<<<16384, 256, 0, stream>>>(Wv, Wvh);

  // G1: [q;k] = Acat(512x12288-folded) * Xcat(12288-folded x 16384)
  gemm128<0><<<dim3(128, 4, 1), 256, 0, stream>>>(
      Acat, 8192, Xcat, 8192, nullptr, bq, bk, q, k, nullptr, nullptr, nullptr, 12288);

  energy_kernel<<<dim3(4, 4, 64), 256, 0, stream>>>(q, k, en);
  softmax_kernel<<<16384, 256, 0, stream>>>(en, atb);

  // G2: zT[b][i][c] = sum_n attn[b][i][n] x[b][c][n]
  gemm128<1><<<dim3(32, 2, 64), 256, 0, stream>>>(
      atb, 256, nullptr, 0, x, nullptr, nullptr, nullptr, nullptr, zT, nullptr, nullptr, 256);

  // G3: out[b][c][i] = sum_k Wvh[c][k] zT[(b,i)][k] + bv[c]
  gemm128<2><<<dim3(128, 32, 1), 256, 0, stream>>>(
      Wvh, 4096, zT, 4096, nullptr, nullptr, nullptr, nullptr, nullptr, nullptr, outF, bv, 4096);
}

// Round 6
// 1664.084 us; speedup vs baseline: 1.0862x; 1.0862x over previous
//
#include <hip/hip_runtime.h>
#include <hip/hip_bf16.h>
#include <stdint.h>

// Problem constants (B,C,D,H,W fixed by the reference)
#define Bsz  64
#define Cch  4096
#define Npos 256     // D*H*W == CQ
#define CQn  256

typedef __attribute__((ext_vector_type(8))) short bf16x8;   // 8 bf16 (4 VGPRs)
typedef __attribute__((ext_vector_type(4))) short s16x4;
typedef __attribute__((ext_vector_type(4))) float f32x4;

static __device__ __forceinline__ unsigned short f2bf(float f){
  union { float f; uint32_t u; } v; v.f = f;
  uint32_t u = v.u;
  u += 0x7FFFu + ((u >> 16) & 1u);        // RNE
  return (unsigned short)(u >> 16);
}
static __device__ __forceinline__ float bf2f(unsigned short h){
  union { uint32_t u; float f; } v; v.u = ((uint32_t)h) << 16; return v.f;
}
static __device__ __forceinline__ void gload_lds16(const unsigned short* g, unsigned short* lds){
  __builtin_amdgcn_global_load_lds((const __attribute__((address_space(1))) void*)g,
                                   (__attribute__((address_space(3))) void*)lds, 16, 0, 0);
}

// ---------------------------------------------------------------------------
// prep: x [B][C][N] f32  ->  Xcat [(b,n)][8192] bf16 : cols 0..4095 = hi(x^T),
//                                                      cols 4096..8191 = lo(x^T)
// ---------------------------------------------------------------------------
__global__ __launch_bounds__(256)
void split_x_kernel(const float* __restrict__ x, unsigned short* __restrict__ Xcat){
  __shared__ float tile[64][65];
  const int b = blockIdx.z, c0 = blockIdx.x * 64, n0 = blockIdx.y * 64;
  const float* xp = x + (size_t)b * Cch * Npos;
  const int t = threadIdx.x;
  #pragma unroll
  for (int p = 0; p < 16; ++p){
    int idx = p * 256 + t;
    int c = idx >> 6, n = idx & 63;
    tile[c][n] = xp[(size_t)(c0 + c) * Npos + n0 + n];
  }
  __syncthreads();
  #pragma unroll
  for (int p = 0; p < 16; ++p){
    int idx = p * 256 + t;
    int n = idx >> 6, c = idx & 63;
    float v = tile[c][n];
    unsigned short hi = f2bf(v);
    unsigned short lo = f2bf(v - bf2f(hi));
    size_t base = ((size_t)(b * 256 + n0 + n) << 13) + (size_t)(c0 + c);
    Xcat[base]        = hi;
    Xcat[base + 4096] = lo;
  }
}

// Acat [512][8192] bf16: rows 0..255 = [hi(Wq) | lo(Wq)], rows 256..511 = [hi(Wk) | lo(Wk)]
__global__ __launch_bounds__(256)
void prep_acat_kernel(const float* __restrict__ Wq, const float* __restrict__ Wk,
                      unsigned short* __restrict__ Acat){
  size_t i = (size_t)blockIdx.x * 256 + threadIdx.x;   // < 512*4096
  int m = (int)(i >> 12), c = (int)(i & 4095);
  float wv = (m < 256) ? Wq[i] : Wk[i - 1048576];
  unsigned short hi = f2bf(wv);
  unsigned short lo = f2bf(wv - bf2f(hi));
  Acat[((size_t)m << 13) + c]        = hi;
  Acat[((size_t)m << 13) + 4096 + c] = lo;
}

__global__ __launch_bounds__(256)
void cast_wv_kernel(const float* __restrict__ Wv, unsigned short* __restrict__ Wvh){
  size_t i = ((size_t)blockIdx.x * 256 + threadIdx.x) * 4;
  f32x4 v = *(const f32x4*)(Wv + i);
  s16x4 h;
  h[0] = (short)f2bf(v[0]); h[1] = (short)f2bf(v[1]);
  h[2] = (short)f2bf(v[2]); h[3] = (short)f2bf(v[3]);
  *(s16x4*)(Wvh + i) = h;
}

// ---------------------------------------------------------------------------
// gemm256_g3: 256x256 tile, 8 waves (2Mx4N), BK=32, 4-slot LDS ring,
// counted vmcnt(8) pipeline (T3+T4), bank-swizzled LDS (T2), setprio (T5).
//   out[b][c][i] = sum_k Wvh[c][k] * zT[(b,i)][k] + bv[c]
// Swizzle: within a 64B LDS row, 16B-slot ^= (row>>1)&3 (balances 32 banks for
// stride-64B fragment reads). global_load_lds dest stays LINEAR; the global
// SOURCE k-offset is pre-swizzled per lane: 8*((l&3)^((l>>3)&3))  [rule #21].
// ---------------------------------------------------------------------------
__global__ __launch_bounds__(512, 2)
void gemm256_g3(const unsigned short* __restrict__ Ag,   // Wvh [4096][4096]
                const unsigned short* __restrict__ Bg,   // zT  [16384][4096]
                const float* __restrict__ bias,          // bv[4096]
                float* __restrict__ outF)                // [64][4096][256]
{
  __shared__ __align__(16) unsigned short ldsA[4][8192];  // 4 slots x 256rows x 32k
  __shared__ __align__(16) unsigned short ldsB[4][8192];
  const int t0 = threadIdx.x;
  const int l = t0 & 63, w = t0 >> 6;
  const int wr = w >> 2, wc = w & 3;          // wave tile: rows wr*128, cols wc*64
  const int bid = blockIdx.x;                  // 1024 blocks, 1024%8==0 -> bijective
  const int sb = (bid & 7) * 128 + (bid >> 3); // XCD-aware swizzle (T1)
  const int row0 = (sb >> 6) * 256;
  const int col0 = (sb & 63) * 256;

  // staging lane constants (per-lane pre-swizzled source)
  const int sRow = l >> 2;                         // 0..15 within 16-row group
  const int sK   = 8 * ((l & 3) ^ ((l >> 3) & 3)); // swizzled source k-offset
  const unsigned short* aSrc = Ag + (size_t)(row0 + w * 16 + sRow) * 4096 + sK;
  const unsigned short* bSrc = Bg + (size_t)(col0 + w * 16 + sRow) * 4096 + sK;
  const size_t halfStride = (size_t)128 * 4096;    // 128 rows down

  // fragment-read constants
  const int fl  = l & 15, g = l >> 4;
  const int swz = (l >> 1) & 3;                    // == ((l&15)>>1)&3
  const int aOff = (wr * 128 + fl) * 32 + 8 * (g ^ swz);
  const int bOff = (wc * 64  + fl) * 32 + 8 * (g ^ swz);

  f32x4 acc[8][4];
  #pragma unroll
  for (int i = 0; i < 8; ++i)
    #pragma unroll
    for (int j = 0; j < 4; ++j) acc[i][j] = (f32x4){0.f, 0.f, 0.f, 0.f};

  // ---- prologue: stage K-steps 0..2 into slots 0..2 (12 loads/thread) ----
  for (int ss = 0; ss < 3; ++ss){
    const int k0 = ss * 32;
    gload_lds16(aSrc + k0,              &ldsA[ss][(w * 16) * 32]);
    gload_lds16(aSrc + halfStride + k0, &ldsA[ss][(128 + w * 16) * 32]);
    gload_lds16(bSrc + k0,              &ldsB[ss][(w * 16) * 32]);
    gload_lds16(bSrc + halfStride + k0, &ldsB[ss][(128 + w * 16) * 32]);
  }

  // ---- main loop: 128 K-steps, 2 phases each, vmcnt never drained ----
  for (int t = 0; t < 128; ++t){
    const int slot  = t & 3;
    const int pslot = (t + 3) & 3;
    const int pk0   = ((t + 3 < 128) ? (t + 3) : 127) * 32;  // clamped restage (dead slots)
    const unsigned short* As = ldsA[slot];
    const unsigned short* Bs = ldsB[slot];

    // phase 1: sync-in (own loads of slot t are the oldest 4 of 12 outstanding)
    asm volatile("s_waitcnt vmcnt(8)" ::: "memory");
    asm volatile("s_barrier" ::: "memory");

    bf16x8 bfr[4];
    #pragma unroll
    for (int nj = 0; nj < 4; ++nj)
      bfr[nj] = *(const bf16x8*)&Bs[bOff + nj * 512];
    bf16x8 af[4];
    #pragma unroll
    for (int mi = 0; mi < 4; ++mi)
      af[mi] = *(const bf16x8*)&As[aOff + mi * 512];
    // prefetch A half-tiles of step t+3 (dest region last read in step t-1)
    gload_lds16(aSrc + pk0,              &ldsA[pslot][(w * 16) * 32]);
    gload_lds16(aSrc + halfStride + pk0, &ldsA[pslot][(128 + w * 16) * 32]);

    asm volatile("s_barrier" ::: "memory");
    __builtin_amdgcn_s_setprio(1);
    #pragma unroll
    for (int mi = 0; mi < 4; ++mi)
      #pragma unroll
      for (int nj = 0; nj < 4; ++nj)
        acc[mi][nj] = __builtin_amdgcn_mfma_f32_16x16x32_bf16(af[mi], bfr[nj], acc[mi][nj], 0, 0, 0);
    __builtin_amdgcn_s_setprio(0);

    // phase 2
    asm volatile("s_barrier" ::: "memory");
    #pragma unroll
    for (int mi = 0; mi < 4; ++mi)
      af[mi] = *(const bf16x8*)&As[aOff + (4 + mi) * 512];
    gload_lds16(bSrc + pk0,              &ldsB[pslot][(w * 16) * 32]);
    gload_lds16(bSrc + halfStride + pk0, &ldsB[pslot][(128 + w * 16) * 32]);

    asm volatile("s_barrier" ::: "memory");
    __builtin_amdgcn_s_setprio(1);
    #pragma unroll
    for (int mi = 0; mi < 4; ++mi)
      #pragma unroll
      for (int nj = 0; nj < 4; ++nj)
        acc[4 + mi][nj] = __builtin_amdgcn_mfma_f32_16x16x32_bf16(af[mi], bfr[nj], acc[4 + mi][nj], 0, 0, 0);
    __builtin_amdgcn_s_setprio(0);
  }
  asm volatile("s_waitcnt vmcnt(0)" ::: "memory");  // drain leftover prefetches

  // ---- epilogue: C-write (D mapping: col=lane&15, row=(lane>>4)*4+r) ----
  #pragma unroll
  for (int mi = 0; mi < 8; ++mi){
    #pragma unroll
    for (int nj = 0; nj < 4; ++nj){
      const int col = col0 + wc * 64 + nj * 16 + fl;
      const int b = col >> 8, i2 = col & 255;
      f32x4 v = acc[mi][nj];
      #pragma unroll
      for (int r = 0; r < 4; ++r){
        const int row = row0 + wr * 128 + mi * 16 + g * 4 + r;
        outF[(size_t)b * ((size_t)Cch * Npos) + (size_t)row * Npos + i2] = v[r] + bias[row];
      }
    }
  }
}

// ---------------------------------------------------------------------------
// Shared 128x128x(BK=64) bf16 MFMA GEMM, m97 structure (G1, G2 still use this).
// ---------------------------------------------------------------------------
template<int MODE>
__global__ __launch_bounds__(256)
void gemm128(const unsigned short* __restrict__ A, int ldA,
             const unsigned short* __restrict__ Bm, int ldB,
             const float* __restrict__ Bf32,
             const float* __restrict__ biasQ, const float* __restrict__ biasK,
             float* __restrict__ outQ, float* __restrict__ outK,
             unsigned short* __restrict__ outBF,
             float* __restrict__ outF, const float* __restrict__ biasV,
             int K)
{
  __shared__ __align__(16) unsigned short As[128 * 64];
  __shared__ __align__(16) unsigned short Bs[128 * 64];
  const int t = threadIdx.x;
  const int w = t >> 6, l = t & 63;
  const int wr = w >> 1, wc = w & 1;
  const int nt = blockIdx.x, mt = blockIdx.y, bz = blockIdx.z;
  const int row0 = mt * 128, col0 = nt * 128;

  const unsigned short* Ab = A;
  const float* xb = Bf32;
  if constexpr (MODE == 1) {
    Ab = A + (size_t)bz * (CQn * Npos);
    xb = Bf32 + (size_t)bz * ((size_t)Cch * Npos);
  }

  f32x4 acc[4][4];
  #pragma unroll
  for (int i = 0; i < 4; ++i)
    #pragma unroll
    for (int j = 0; j < 4; ++j) acc[i][j] = (f32x4){0.f, 0.f, 0.f, 0.f};

  const int lr8 = l >> 3;
  const int lk8 = (l & 7) * 8;
  const int fl  = l & 15;
  const int fk  = (l >> 4) * 8;

  const int nsteps = K >> 6;
  for (int kt = 0; kt < nsteps; ++kt){
    const int k0 = kt << 6;
    __syncthreads();
    {
      int ak = k0;
      if constexpr (MODE == 0) ak = (k0 < 4096) ? k0 : k0 - 4096;
      const unsigned short* Ab2 = Ab + (size_t)row0 * ldA + ak + lk8;
      #pragma unroll
      for (int r = 0; r < 4; ++r){
        int rr = r * 32 + w * 8 + lr8;
        gload_lds16(Ab2 + (size_t)rr * ldA, &As[(r * 32 + w * 8) * 64]);
      }
    }
    if constexpr (MODE == 1){
      #pragma unroll
      for (int p = 0; p < 8; ++p){
        int c = p * 16 + (t >> 4);
        int slot = t & 15;
        f32x4 v = *(const f32x4*)(xb + (size_t)(col0 + c) * Npos + k0 + slot * 4);
        s16x4 h;
        h[0] = (short)f2bf(v[0]); h[1] = (short)f2bf(v[1]);
        h[2] = (short)f2bf(v[2]); h[3] = (short)f2bf(v[3]);
        *(s16x4*)&Bs[c * 64 + slot * 4] = h;
      }
    } else {
      int bk = k0;
      if constexpr (MODE == 0) bk = (k0 < 8192) ? k0 : k0 - 8192;
      const unsigned short* Bb2 = Bm + (size_t)col0 * ldB + bk + lk8;
      #pragma unroll
      for (int r = 0; r < 4; ++r){
        int rr = r * 32 + w * 8 + lr8;
        gload_lds16(Bb2 + (size_t)rr * ldB, &Bs[(r * 32 + w * 8) * 64]);
      }
    }
    __syncthreads();
    #pragma unroll
    for (int kk = 0; kk < 2; ++kk){
      bf16x8 af[4], bfr[4];
      #pragma unroll
      for (int mi = 0; mi < 4; ++mi)
        af[mi] = *(const bf16x8*)&As[(wr * 64 + mi * 16 + fl) * 64 + kk * 32 + fk];
      #pragma unroll
      for (int nj = 0; nj < 4; ++nj)
        bfr[nj] = *(const bf16x8*)&Bs[(wc * 64 + nj * 16 + fl) * 64 + kk * 32 + fk];
      #pragma unroll
      for (int mi = 0; mi < 4; ++mi)
        #pragma unroll
        for (int nj = 0; nj < 4; ++nj)
          acc[mi][nj] = __builtin_amdgcn_mfma_f32_16x16x32_bf16(af[mi], bfr[nj], acc[mi][nj], 0, 0, 0);
    }
  }

  const int lrow = (l >> 4) * 4;
  #pragma unroll
  for (int mi = 0; mi < 4; ++mi){
    #pragma unroll
    for (int nj = 0; nj < 4; ++nj){
      int col = col0 + wc * 64 + nj * 16 + fl;
      f32x4 v = acc[mi][nj];
      #pragma unroll
      for (int r = 0; r < 4; ++r){
        int row = row0 + wr * 64 + mi * 16 + lrow + r;
        if constexpr (MODE == 0){
          int b = col >> 8, n = col & 255;
          float bia = (row < 256) ? biasQ[row] : biasK[row - 256];
          float* dst = (row < 256) ? outQ : outK;
          dst[((size_t)b << 16) + ((size_t)(row & 255) << 8) + n] = v[r] + bia;
        } else if constexpr (MODE == 1){
          outBF[(size_t)bz * ((size_t)CQn * Cch) + (size_t)row * Cch + col] = f2bf(v[r]);
        } else {
          int b = col >> 8, i2 = col & 255;
          outF[(size_t)b * ((size_t)Cch * Npos) + (size_t)row * Npos + i2] = v[r] + biasV[row];
        }
      }
    }
  }
}

// ---------------------------------------------------------------------------
// energy[b][i][j] = sum_n q[b][i][n] * k[b][j][n]   (fp32 vector, NT GEMM)
// ---------------------------------------------------------------------------
__global__ __launch_bounds__(256)
void energy_kernel(const float* __restrict__ q, const float* __restrict__ k,
                   float* __restrict__ e){
  const int b = blockIdx.z;
  const int i0 = blockIdx.y * 64, j0 = blockIdx.x * 64;
  const float* qb = q + ((size_t)b << 16);
  const float* kb = k + ((size_t)b << 16);
  float* eb = e + ((size_t)b << 16);
  __shared__ float Qs[64][33];
  __shared__ float Ks[64][33];
  const int t = threadIdx.x;
  const int tx = t & 15, ty = t >> 4;
  float accv[4][4];
  #pragma unroll
  for (int ii = 0; ii < 4; ++ii)
    #pragma unroll
    for (int jj = 0; jj < 4; ++jj) accv[ii][jj] = 0.f;

  for (int n0 = 0; n0 < 256; n0 += 32){
    __syncthreads();
    #pragma unroll
    for (int p = 0; p < 8; ++p){
      int idx = p * 256 + t;
      int r = idx >> 5, n = idx & 31;
      Qs[r][n] = qb[(size_t)(i0 + r) * 256 + n0 + n];
      Ks[r][n] = kb[(size_t)(j0 + r) * 256 + n0 + n];
    }
    __syncthreads();
    #pragma unroll
    for (int n = 0; n < 32; ++n){
      float a4[4], b4[4];
      #pragma unroll
      for (int ii = 0; ii < 4; ++ii) a4[ii] = Qs[ty * 4 + ii][n];
      #pragma unroll
      for (int jj = 0; jj < 4; ++jj) b4[jj] = Ks[tx * 4 + jj][n];
      #pragma unroll
      for (int ii = 0; ii < 4; ++ii)
        #pragma unroll
        for (int jj = 0; jj < 4; ++jj) accv[ii][jj] = fmaf(a4[ii], b4[jj], accv[ii][jj]);
    }
  }
  #pragma unroll
  for (int ii = 0; ii < 4; ++ii){
    f32x4 o;
    #pragma unroll
    for (int jj = 0; jj < 4; ++jj) o[jj] = accv[ii][jj];
    *(f32x4*)&eb[(size_t)(i0 + ty * 4 + ii) * 256 + j0 + tx * 4] = o;
  }
}

// softmax over last axis (256), write bf16 attn
__global__ __launch_bounds__(256)
void softmax_kernel(const float* __restrict__ e, unsigned short* __restrict__ attn){
  const size_t row = blockIdx.x;
  const int t = threadIdx.x;
  float v = e[(row << 8) + t];
  float m = v;
  #pragma unroll
  for (int off = 32; off >= 1; off >>= 1) m = fmaxf(m, __shfl_xor(m, off));
  __shared__ float red[8];
  if ((t & 63) == 0) red[t >> 6] = m;
  __syncthreads();
  m = fmaxf(fmaxf(red[0], red[1]), fmaxf(red[2], red[3]));
  float p = __expf(v - m);
  float s = p;
  #pragma unroll
  for (int off = 32; off >= 1; off >>= 1) s += __shfl_xor(s, off);
  if ((t & 63) == 0) red[4 + (t >> 6)] = s;
  __syncthreads();
  s = red[4] + red[5] + red[6] + red[7];
  attn[(row << 8) + t] = f2bf(p / s);
}

// ---------------------------------------------------------------------------
extern "C" void kernel_launch(void* const* d_in, const int* in_sizes, int n_in,
                              void* d_out, int out_size, void* d_ws, size_t ws_size,
                              hipStream_t stream){
  const float* x  = (const float*)d_in[0];
  const float* Wq = (const float*)d_in[1];
  const float* bq = (const float*)d_in[2];
  const float* Wk = (const float*)d_in[3];
  const float* bk = (const float*)d_in[4];
  const float* Wv = (const float*)d_in[5];
  const float* bv = (const float*)d_in[6];

  // workspace layout (310,378,496 B total):
  //   [0, 268435456)              Xcat bf16 [16384][8192]  (hi | lo of x^T)
  //   [0, 134217728)  (overlay)   zT bf16 [16384][4096]    (written after Xcat dead)
  //   [268435456, +8388608)       Acat bf16 [512][8192]
  //   [276824064, +33554432)      Wvh  bf16 [4096][4096]
  char* ws = (char*)d_ws;
  unsigned short* Xcat = (unsigned short*)ws;
  unsigned short* zT   = (unsigned short*)ws;                       // overlay
  unsigned short* Acat = (unsigned short*)(ws + 268435456u);
  unsigned short* Wvh  = (unsigned short*)(ws + 268435456u + 8388608u);

  // d_out doubles as scratch for q/k/energy/attn (all dead before the final GEMM)
  char* ob = (char*)d_out;
  float* q            = (float*)ob;                       // 16.8 MB
  float* k            = (float*)(ob + 16777216u);         // 16.8 MB
  float* en           = (float*)(ob + 33554432u);         // 16.8 MB
  unsigned short* atb = (unsigned short*)(ob + 50331648u);// 8.4 MB
  float* outF         = (float*)d_out;

  split_x_kernel<<<dim3(64, 4, 64), 256, 0, stream>>>(x, Xcat);
  prep_acat_kernel<<<8192, 256, 0, stream>>>(Wq, Wk, Acat);
  cast_wv_kernel<<<16384, 256, 0, stream>>>(Wv, Wvh);

  // G1: [q;k] = Acat(512x12288-folded) * Xcat(12288-folded x 16384)
  gemm128<0><<<dim3(128, 4, 1), 256, 0, stream>>>(
      Acat, 8192, Xcat, 8192, nullptr, bq, bk, q, k, nullptr, nullptr, nullptr, 12288);

  energy_kernel<<<dim3(4, 4, 64), 256, 0, stream>>>(q, k, en);
  softmax_kernel<<<16384, 256, 0, stream>>>(en, atb);

  // G2: zT[b][i][c] = sum_n attn[b][i][n] x[b][c][n]
  gemm128<1><<<dim3(32, 2, 64), 256, 0, stream>>>(
      atb, 256, nullptr, 0, x, nullptr, nullptr, nullptr, nullptr, zT, nullptr, nullptr, 256);

  // G3: out[b][c][i] = sum_k Wvh[c][k] zT[(b,i)][k] + bv[c]   (8-wave pipelined)
  gemm256_g3<<<1024, 512, 0, stream>>>(Wvh, zT, bv, outF);
}